// Round 12
// baseline (334.299 us; speedup 1.0000x reference)
//
#include <hip/hip_runtime.h>
#include <hip/hip_bf16.h>
#include <math.h>

// Problem constants
#define B_    8
#define CDIM  512
#define HW    4096
#define CI_   64
#define MT    64            // kv rows per tile
#define NTIL  (HW/MT)       // 64 tiles

typedef __attribute__((ext_vector_type(8))) short bf16x8;
typedef __attribute__((ext_vector_type(4))) float f32x4;
typedef __attribute__((ext_vector_type(16))) float f32x16;
typedef unsigned short u16;
typedef unsigned int   u32;

union fragu { bf16x8 v; u32 w[4]; };

// fp32 -> bf16 bits with RNE rounding
__device__ __forceinline__ u32 bfr(float f) {
  u32 x = __float_as_uint(f);
  return (x + 0x7fffu + ((x >> 16) & 1u)) >> 16;
}
// packed 2xf32 -> bf16x2 (RNE) via HW instruction
__device__ __forceinline__ u32 cvtpk(float a, float b) {
  u32 r;
  asm("v_cvt_pk_bf16_f32 %0, %1, %2" : "=v"(r) : "v"(a), "v"(b));
  return r;
}
// raw v_exp_f32 = exp2 (log2e is pre-folded into Q's projection scale)
__device__ __forceinline__ float hexp2(float x) {
  float r;
  asm("v_exp_f32 %0, %1" : "=v"(r) : "v"(x));
  return r;
}
// W row (f32, k-contiguous 8) -> bf16x8 fragment
__device__ __forceinline__ bf16x8 wfrag(const float* wrow) {
  float4 w0 = *(const float4*)wrow;
  float4 w1 = *(const float4*)(wrow + 4);
  fragu f;
  f.w[0] = cvtpk(w0.x, w0.y); f.w[1] = cvtpk(w0.z, w0.w);
  f.w[2] = cvtpk(w1.x, w1.y); f.w[3] = cvtpk(w1.z, w1.w);
  return f.v;
}

// global -> LDS direct DMA, 16B/lane (dest = wave-uniform base + lane*16, linear)
typedef const __attribute__((address_space(1))) void g1cv;
typedef __attribute__((address_space(3))) void l3v;
#define GLDS16(g, l) __builtin_amdgcn_global_load_lds((g1cv*)(g), (l3v*)(l), 16, 0, 0)

#define MFMA16(a, b, c) __builtin_amdgcn_mfma_f32_16x16x32_bf16(a, b, c, 0, 0, 0)

// ---------------- unified projection kernel (single launch, two roles) ----------------
// blocks [0,512):   Q/K projection with fused transpose+cast.
//   D[n,o] = (sum_c X[c,n] W[o,c] + bias[o]) * alpha; z<8 -> Q (alpha=0.125*log2e), else K.
// blocks [512,2560): V^T projection. V^T[c_out,m] = sum_c Wv[c_out,c] value[c,m] + bv.
// Weights read directly as f32 (L1-hot) and packed per-use via cvt_pk (RNE == cast3).
__global__ __launch_bounds__(256) void proj_all(
    const float* __restrict__ query, const float* __restrict__ key,
    const float* __restrict__ value,
    const float* __restrict__ Wq, const float* __restrict__ Wk,
    const float* __restrict__ Wv,
    const float* __restrict__ bq, const float* __restrict__ bk,
    const float* __restrict__ bv,
    u16* __restrict__ Qo, u16* __restrict__ Ko, u16* __restrict__ Vo)
{
  __shared__ __align__(16) char smem[66048];   // qk: 2 x 64x129 f32; v: 2 x 64x65 f32

  const int bid = blockIdx.x;
  const int tid = threadIdx.x, wid = tid >> 6, lane = tid & 63;
  const int lr = lane & 15, lg = lane >> 4;
  const int srow = tid >> 3;            // staging: 0..31
  const int scol = (tid & 7) * 4;       // f32 col base

  if (bid < 512) {
    // ================= Q/K role =================
    const int xb = bid & 31, z = bid >> 5;
    const bool isq = z < 8;
    const int bz = isq ? z : z - 8;
    const float* X = (isq ? query : key) + (size_t)bz * CDIM * HW;
    const float* W = isq ? Wq : Wk;
    const float* bias = isq ? bq : bk;
    const float alpha = isq ? 0.125f * 1.44269504f : 1.0f;
    u16* D = (isq ? Qo : Ko) + (size_t)bz * HW * CI_;
    const int n0 = xb * 128;

    float* Xs0 = (float*)smem;
    uint4 sx[2][4];

#define PQLOAD(T) do { \
    _Pragma("unroll") \
    for (int p = 0; p < 2; ++p) \
      _Pragma("unroll") \
      for (int jj = 0; jj < 4; ++jj) \
        sx[p][jj] = *(const uint4*)(X + (size_t)((T) * 64 + srow + 32 * p) * HW + n0 + scol + 32 * jj); \
  } while (0)
#define PQWRITE(BUF) do { \
    float* _d = Xs0 + (BUF) * 64 * 129; \
    _Pragma("unroll") \
    for (int p = 0; p < 2; ++p) \
      _Pragma("unroll") \
      for (int jj = 0; jj < 4; ++jj) \
        *(uint4*)(&_d[(srow + 32 * p) * 129 + scol + 32 * jj]) = sx[p][jj]; \
  } while (0)

    f32x4 acc[2][4];
#pragma unroll
    for (int rt = 0; rt < 2; ++rt)
#pragma unroll
      for (int ct = 0; ct < 4; ++ct) acc[rt][ct] = (f32x4){0.f, 0.f, 0.f, 0.f};

    PQLOAD(0); PQWRITE(0);
    __syncthreads();

    for (int t = 0; t < 8; ++t) {
      const float* Xs = Xs0 + (t & 1) * 64 * 129;
      if (t + 1 < 8) PQLOAD(t + 1);

#pragma unroll
      for (int kk = 0; kk < 2; ++kk) {
        bf16x8 af[2];
#pragma unroll
        for (int rt = 0; rt < 2; ++rt) {
          const float* col = &Xs[(kk * 32 + lg * 8) * 129 + wid * 32 + rt * 16 + lr];
          fragu fu;
#pragma unroll
          for (int j = 0; j < 4; ++j)
            fu.w[j] = cvtpk(col[(2 * j) * 129], col[(2 * j + 1) * 129]);
          af[rt] = fu.v;
        }
#pragma unroll
        for (int ct = 0; ct < 4; ++ct) {
          bf16x8 bf = wfrag(W + (size_t)(ct * 16 + lr) * CDIM + t * 64 + kk * 32 + lg * 8);
          acc[0][ct] = MFMA16(af[0], bf, acc[0][ct]);
          acc[1][ct] = MFMA16(af[1], bf, acc[1][ct]);
        }
      }

      if (t + 1 < 8) PQWRITE((t + 1) & 1);
      __syncthreads();
    }

#pragma unroll
    for (int rt = 0; rt < 2; ++rt)
#pragma unroll
      for (int ct = 0; ct < 4; ++ct)
#pragma unroll
        for (int r = 0; r < 4; ++r) {
          int i = n0 + wid * 32 + rt * 16 + lg * 4 + r;
          int j = ct * 16 + lr;
          D[(size_t)i * CI_ + j] = (u16)bfr((acc[rt][ct][r] + bias[j]) * alpha);
        }
  } else {
    // ================= V role =================
    const int vb = bid - 512;
    const int xc = vb & 3, ym = (vb >> 2) & 63, bz = vb >> 8;
    const float* X = value + (size_t)bz * CDIM * HW;
    u16* D = Vo + (size_t)bz * CDIM * HW;
    const int i0 = xc * 128 + wid * 32;   // c_out base (wave)
    const int j0 = ym * 64;               // m base (block)

    float* Vs0 = (float*)smem;
    uint4 sv[2][2];

#define PVLOAD(T) do { \
    _Pragma("unroll") \
    for (int p = 0; p < 2; ++p) \
      _Pragma("unroll") \
      for (int jj = 0; jj < 2; ++jj) \
        sv[p][jj] = *(const uint4*)(X + (size_t)((T) * 64 + srow + 32 * p) * HW + j0 + scol + 32 * jj); \
  } while (0)
#define PVWRITE(BUF) do { \
    float* _d = Vs0 + (BUF) * 64 * 65; \
    _Pragma("unroll") \
    for (int p = 0; p < 2; ++p) \
      _Pragma("unroll") \
      for (int jj = 0; jj < 2; ++jj) \
        *(uint4*)(&_d[(srow + 32 * p) * 65 + scol + 32 * jj]) = sv[p][jj]; \
  } while (0)

    f32x4 acc[2][4];
#pragma unroll
    for (int rt = 0; rt < 2; ++rt)
#pragma unroll
      for (int ct = 0; ct < 4; ++ct) acc[rt][ct] = (f32x4){0.f, 0.f, 0.f, 0.f};

    PVLOAD(0); PVWRITE(0);
    __syncthreads();

    for (int t = 0; t < 8; ++t) {
      const float* Vsf = Vs0 + (t & 1) * 64 * 65;
      if (t + 1 < 8) PVLOAD(t + 1);

#pragma unroll
      for (int kk = 0; kk < 2; ++kk) {
        bf16x8 af[2];
#pragma unroll
        for (int rt = 0; rt < 2; ++rt)
          af[rt] = wfrag(Wv + (size_t)(i0 + rt * 16 + lr) * CDIM + t * 64 + kk * 32 + lg * 8);
#pragma unroll
        for (int ct = 0; ct < 4; ++ct) {
          const float* col = &Vsf[(kk * 32 + lg * 8) * 65 + ct * 16 + lr];
          fragu fu;
#pragma unroll
          for (int j = 0; j < 4; ++j)
            fu.w[j] = cvtpk(col[(2 * j) * 65], col[(2 * j + 1) * 65]);
          bf16x8 bf = fu.v;
          acc[0][ct] = MFMA16(af[0], bf, acc[0][ct]);
          acc[1][ct] = MFMA16(af[1], bf, acc[1][ct]);
        }
      }

      if (t + 1 < 8) PVWRITE((t + 1) & 1);
      __syncthreads();
    }

#pragma unroll
    for (int rt = 0; rt < 2; ++rt)
#pragma unroll
      for (int ct = 0; ct < 4; ++ct)
#pragma unroll
        for (int r = 0; r < 4; ++r) {
          int i = i0 + rt * 16 + lg * 4 + r;
          int j = j0 + ct * 16 + lr;
          D[(size_t)i * HW + j] = (u16)bfr(acc[rt][ct][r] + bv[i]);
        }
  }
}

// ---------------- fused flash attention + gamma*attn + value ----------------
// R10/R11 kernel, byte-identical (measured 235-236us x2: GLDS pre-swizzled staging + exp2 fold).
__global__ __launch_bounds__(256, 2) void flash_attn(
    const u16* __restrict__ Q, const u16* __restrict__ K, const u16* __restrict__ V,
    const float* __restrict__ value, const float* __restrict__ gammap, float* __restrict__ out)
{
  __shared__ u16 Ks[2][64 * 64];     // 2 x 8 KB   [m=64][ci=64], swizzled chunks
  __shared__ u16 Vs[2][128 * 64];    // 2 x 16 KB  [c=128][m=64], swizzled chunks

  const int b  = blockIdx.x & 7;
  const int rb = (blockIdx.x >> 3) & 15;
  const int ch = blockIdx.x >> 7;
  const int tid = threadIdx.x, wid = tid >> 6, lane = tid & 63;
  const int l31 = lane & 31, h = lane >> 5;

  const int n0 = rb * 256 + wid * 64;   // wave q-row base
  const int c0 = ch * 128;              // block c base

  const u16* Qb = Q + (size_t)b * HW * CI_;
  const u16* Kb = K + (size_t)b * HW * CI_;
  const u16* Vb = V + (size_t)b * CDIM * HW + (size_t)c0 * HW;

  // Q B-frags: col n = n0 + ng*32 + l31, k = kk*16 + h*8 + j
  bf16x8 qf[2][4];
#pragma unroll
  for (int ng = 0; ng < 2; ++ng)
#pragma unroll
    for (int kk = 0; kk < 4; ++kk)
      qf[ng][kk] = *(const bf16x8*)(Qb + (size_t)(n0 + ng * 32 + l31) * CI_ + kk * 16 + h * 8);

  f32x16 acc[2][4];
#pragma unroll
  for (int ng = 0; ng < 2; ++ng)
#pragma unroll
    for (int ct = 0; ct < 4; ++ct)
#pragma unroll
      for (int i = 0; i < 16; ++i) acc[ng][ct][i] = 0.f;
  float lp0 = 0.f, lp1 = 0.f;

  // ---- staging sources (pre-swizzled): lane -> (row = 8-block + lane>>3, chunk = lane&7)
  const int lrow = lane >> 3, lchk = lane & 7;
  const int swz = lchk ^ lrow;
  const u16* kcur = Kb + (size_t)(wid * 16 + lrow) * CI_ + swz * 8;
  const u16* vcur = Vb + (size_t)(wid * 32 + lrow) * HW + swz * 8;
  const int kofs = wid * 16 * 64, vofs = wid * 32 * 64;   // u16 LDS offsets

#define ISSUE(BUF) do { \
    GLDS16(kcur,              &Ks[BUF][kofs]); \
    GLDS16(kcur + 8 * CI_,    &Ks[BUF][kofs + 8 * 64]); \
    GLDS16(vcur,              &Vs[BUF][vofs]); \
    GLDS16(vcur + 8 * HW,     &Vs[BUF][vofs + 8 * 64]); \
    GLDS16(vcur + 16 * HW,    &Vs[BUF][vofs + 16 * 64]); \
    GLDS16(vcur + 24 * HW,    &Vs[BUF][vofs + 24 * 64]); \
  } while (0)

  ISSUE(0);
  __syncthreads();   // compiler-inserted vmcnt(0) drains the DMA

  for (int t = 0; t < NTIL; ++t) {
    const int par = t & 1;
    if (t + 1 < NTIL) {            // issue next-tile DMA; drains at this tile's end barrier
      kcur += MT * CI_;
      vcur += MT;
      ISSUE(par ^ 1);
    }

#pragma unroll
    for (int s = 0; s < 2; ++s) {  // m-strip of 32 within the 64-m tile
      // K A-frags: row m = s*32 + l31, chunk j = 2kk+h, swizzled by (m&7)==(l31&7)
      bf16x8 kf[4];
#pragma unroll
      for (int kk = 0; kk < 4; ++kk)
        kf[kk] = *(const bf16x8*)(&Ks[par][(s * 32 + l31) * 64 + (((2 * kk + h) ^ (l31 & 7)) << 3)]);

      bf16x8 pa[2][2];             // [ng][kk-local] PV B-frags for this strip
#pragma unroll
      for (int ng = 0; ng < 2; ++ng) {
        f32x16 st;
#pragma unroll
        for (int i = 0; i < 16; ++i) st[i] = 0.f;
#pragma unroll
        for (int kk = 0; kk < 4; ++kk)
          st = __builtin_amdgcn_mfma_f32_32x32x16_bf16(kf[kk], qf[ng][kk], st, 0, 0, 0);

        // P = exp2(S) (log2e pre-folded); row-sum partial
        float p[16]; float rs = 0.f;
#pragma unroll
        for (int r = 0; r < 16; ++r) { p[r] = hexp2(st[r]); rs += p[r]; }
        if (ng == 0) lp0 += rs; else lp1 += rs;

        // T12 pack: quads m(r) = (r&3) + 8*(r>>2) + 4h (within strip)
        u32 qa0 = cvtpk(p[0],  p[1]),  qa1 = cvtpk(p[2],  p[3]);   // m 4h+0..3
        u32 qb0 = cvtpk(p[4],  p[5]),  qb1 = cvtpk(p[6],  p[7]);   // m 8+4h+0..3
        u32 qc0 = cvtpk(p[8],  p[9]),  qc1 = cvtpk(p[10], p[11]);  // m 16+4h+0..3
        u32 qd0 = cvtpk(p[12], p[13]), qd1 = cvtpk(p[14], p[15]);  // m 24+4h+0..3
        asm("v_permlane32_swap_b32 %0, %1" : "+v"(qa0), "+v"(qb0));
        asm("v_permlane32_swap_b32 %0, %1" : "+v"(qa1), "+v"(qb1));
        asm("v_permlane32_swap_b32 %0, %1" : "+v"(qc0), "+v"(qd0));
        asm("v_permlane32_swap_b32 %0, %1" : "+v"(qc1), "+v"(qd1));
        fragu f0; f0.w[0] = qa0; f0.w[1] = qa1; f0.w[2] = qb0; f0.w[3] = qb1;
        pa[ng][0] = f0.v;
        fragu f1; f1.w[0] = qc0; f1.w[1] = qc1; f1.w[2] = qd0; f1.w[3] = qd1;
        pa[ng][1] = f1.v;
      }

      // PV partial for this strip: V chunk j = 4s + 2kkl + h, swizzled by (c&7)==(l31&7)
      __builtin_amdgcn_s_setprio(1);
#pragma unroll
      for (int ct = 0; ct < 4; ++ct)
#pragma unroll
        for (int kkl = 0; kkl < 2; ++kkl) {
          bf16x8 vf = *(const bf16x8*)(&Vs[par][(ct * 32 + l31) * 64 + (((4 * s + 2 * kkl + h) ^ (l31 & 7)) << 3)]);
          acc[0][ct] = __builtin_amdgcn_mfma_f32_32x32x16_bf16(vf, pa[0][kkl], acc[0][ct], 0, 0, 0);
          acc[1][ct] = __builtin_amdgcn_mfma_f32_32x32x16_bf16(vf, pa[1][kkl], acc[1][ct], 0, 0, 0);
        }
      __builtin_amdgcn_s_setprio(0);
    }

    __syncthreads();   // single barrier: drains next-tile DMA + fences dbuf parity
  }

  // ---- epilogue: per-wave LDS transpose so value/out stay coalesced ----
  __syncthreads();   // everyone done with Ks/Vs; reuse as scratch
  float* Tls = (float*)((char*)&Vs[0][0] + wid * 4352);  // 32c x 33n f32 = 4224B per wave
  const float g = gammap[0];
  const float ls0 = lp0 + __shfl_xor(lp0, 32);
  const float ls1 = lp1 + __shfl_xor(lp1, 32);
  const float ri0 = g / ls0, ri1 = g / ls1;   // gamma folded; lane's n = l31 (per ng)
  const size_t obase = (size_t)b * CDIM * HW;
#pragma unroll
  for (int ng = 0; ng < 2; ++ng) {
    const float ri = ng ? ri1 : ri0;
#pragma unroll
    for (int ct = 0; ct < 4; ++ct) {
#pragma unroll
      for (int r = 0; r < 16; ++r) {
        int cc = (r & 3) + 8 * (r >> 2) + 4 * h;
        Tls[cc * 33 + l31] = acc[ng][ct][r] * ri;
      }
#pragma unroll
      for (int p = 0; p < 16; ++p) {
        float v = Tls[l31 * 33 + 2 * p + h];
        int n = n0 + ng * 32 + 2 * p + h;
        int c = c0 + ct * 32 + l31;
        size_t idx = obase + (size_t)n * CDIM + c;
        out[idx] = v + value[idx];
      }
    }
  }
}

extern "C" void kernel_launch(void* const* d_in, const int* in_sizes, int n_in,
                              void* d_out, int out_size, void* d_ws, size_t ws_size,
                              hipStream_t stream) {
  const float* query = (const float*)d_in[0];
  const float* key   = (const float*)d_in[1];
  const float* value = (const float*)d_in[2];
  const float* Wq    = (const float*)d_in[3];
  const float* bq    = (const float*)d_in[4];
  const float* Wk    = (const float*)d_in[5];
  const float* bk    = (const float*)d_in[6];
  const float* Wv    = (const float*)d_in[7];
  const float* bv    = (const float*)d_in[8];
  const float* gamma = (const float*)d_in[9];

  char* ws = (char*)d_ws;
  u16* Qb = (u16*)(ws);                //  4,194,304 B  [B,HW,CI]
  u16* Kb = (u16*)(ws + 4194304);      //  4,194,304 B  [B,HW,CI]
  u16* Vb = (u16*)(ws + 8388608);      // 33,554,432 B  [B,C,HW] V^T

  // 1) all projections (Q, K, V^T) in one launch; weights cast in-kernel
  proj_all<<<2560, 256, 0, stream>>>(
      query, key, value, Wq, Wk, Wv, bq, bk, bv, Qb, Kb, Vb);

  // 2) fused flash attention + epilogue
  flash_attn<<<512, 256, 0, stream>>>(Qb, Kb, Vb, value, gamma, (float*)d_out);
}

// Round 13
// 270.923 us; speedup vs baseline: 1.2339x; 1.2339x over previous
//
#include <hip/hip_runtime.h>
#include <hip/hip_bf16.h>
#include <math.h>

// Problem constants
#define B_    8
#define CDIM  512
#define HW    4096
#define CI_   64
#define MT    64            // kv rows per tile
#define NTIL  (HW/MT)       // 64 tiles

typedef __attribute__((ext_vector_type(8))) short bf16x8;
typedef __attribute__((ext_vector_type(4))) float f32x4;
typedef __attribute__((ext_vector_type(16))) float f32x16;
typedef unsigned short u16;
typedef unsigned int   u32;

union fragu { bf16x8 v; u32 w[4]; };

// fp32 -> bf16 bits with RNE rounding
__device__ __forceinline__ u32 bfr(float f) {
  u32 x = __float_as_uint(f);
  return (x + 0x7fffu + ((x >> 16) & 1u)) >> 16;
}
// packed 2xf32 -> bf16x2 (RNE) via HW instruction
__device__ __forceinline__ u32 cvtpk(float a, float b) {
  u32 r;
  asm("v_cvt_pk_bf16_f32 %0, %1, %2" : "=v"(r) : "v"(a), "v"(b));
  return r;
}
// raw v_exp_f32 = exp2 (log2e is pre-folded into Q's projection scale)
__device__ __forceinline__ float hexp2(float x) {
  float r;
  asm("v_exp_f32 %0, %1" : "=v"(r) : "v"(x));
  return r;
}

// global -> LDS direct DMA, 16B/lane (dest = wave-uniform base + lane*16, linear)
typedef const __attribute__((address_space(1))) void g1cv;
typedef __attribute__((address_space(3))) void l3v;
#define GLDS16(g, l) __builtin_amdgcn_global_load_lds((g1cv*)(g), (l3v*)(l), 16, 0, 0)

#define MFMA16(a, b, c) __builtin_amdgcn_mfma_f32_16x16x32_bf16(a, b, c, 0, 0, 0)

// ---------------- cast fp32 -> bf16 for the three weight tensors (R11) ----------------
__global__ void cast3(const float* __restrict__ wq, const float* __restrict__ wk,
                      const float* __restrict__ wv, u16* __restrict__ oq,
                      u16* __restrict__ ok, u16* __restrict__ ov) {
  int i = blockIdx.x * 256 + threadIdx.x;
  if (i < CI_ * CDIM) { oq[i] = (u16)bfr(wq[i]); ok[i] = (u16)bfr(wk[i]); }
  ov[i] = (u16)bfr(wv[i]);   // grid sized to CDIM*CDIM
}

// ---------------- fused Q/K projection (R11, measured-good) ----------------
__global__ __launch_bounds__(256) void proj_qk(
    const float* __restrict__ query, const float* __restrict__ key,
    const u16* __restrict__ Wq, const u16* __restrict__ Wk,
    const float* __restrict__ bq, const float* __restrict__ bk,
    u16* __restrict__ Qo, u16* __restrict__ Ko)
{
  __shared__ float Xs[2][64 * 129];   // 2 x 33 KB

  const int z = blockIdx.z;
  const bool isq = z < 8;
  const int bz = isq ? z : z - 8;
  const float* X = (isq ? query : key) + (size_t)bz * CDIM * HW;
  const u16* W = isq ? Wq : Wk;
  const float* bias = isq ? bq : bk;
  const float alpha = isq ? 0.125f * 1.44269504f : 1.0f;
  u16* D = (isq ? Qo : Ko) + (size_t)bz * HW * CI_;

  const int tid = threadIdx.x, wid = tid >> 6, lane = tid & 63;
  const int lr = lane & 15, lg = lane >> 4;
  const int n0 = blockIdx.x * 128;

  const int srow = tid >> 3;            // 0..31
  const int scol = (tid & 7) * 4;       // f32 col base; + 32*jj
  uint4 sx[2][4];

#define PQLOAD(T) do { \
    _Pragma("unroll") \
    for (int p = 0; p < 2; ++p) \
      _Pragma("unroll") \
      for (int jj = 0; jj < 4; ++jj) \
        sx[p][jj] = *(const uint4*)(X + (size_t)((T) * 64 + srow + 32 * p) * HW + n0 + scol + 32 * jj); \
  } while (0)
#define PQWRITE(BUF) do { \
    _Pragma("unroll") \
    for (int p = 0; p < 2; ++p) \
      _Pragma("unroll") \
      for (int jj = 0; jj < 4; ++jj) \
        *(uint4*)(&Xs[BUF][(srow + 32 * p) * 129 + scol + 32 * jj]) = sx[p][jj]; \
  } while (0)

  f32x4 acc[2][4];
#pragma unroll
  for (int rt = 0; rt < 2; ++rt)
#pragma unroll
    for (int ct = 0; ct < 4; ++ct) acc[rt][ct] = (f32x4){0.f, 0.f, 0.f, 0.f};

  PQLOAD(0); PQWRITE(0);
  __syncthreads();

  for (int t = 0; t < 8; ++t) {
    const int par = t & 1;
    if (t + 1 < 8) PQLOAD(t + 1);

#pragma unroll
    for (int kk = 0; kk < 2; ++kk) {
      bf16x8 af[2];
#pragma unroll
      for (int rt = 0; rt < 2; ++rt) {
        const float* col = &Xs[par][(kk * 32 + lg * 8) * 129 + wid * 32 + rt * 16 + lr];
        fragu fu;
#pragma unroll
        for (int j = 0; j < 4; ++j)
          fu.w[j] = cvtpk(col[(2 * j) * 129], col[(2 * j + 1) * 129]);
        af[rt] = fu.v;
      }
#pragma unroll
      for (int ct = 0; ct < 4; ++ct) {
        bf16x8 bf = *(const bf16x8*)(W + (size_t)(ct * 16 + lr) * CDIM + t * 64 + kk * 32 + lg * 8);
        acc[0][ct] = MFMA16(af[0], bf, acc[0][ct]);
        acc[1][ct] = MFMA16(af[1], bf, acc[1][ct]);
      }
    }

    if (t + 1 < 8) PQWRITE((t + 1) & 1);
    __syncthreads();
  }

#pragma unroll
  for (int rt = 0; rt < 2; ++rt)
#pragma unroll
    for (int ct = 0; ct < 4; ++ct)
#pragma unroll
      for (int r = 0; r < 4; ++r) {
        int i = n0 + wid * 32 + rt * 16 + lg * 4 + r;
        int j = ct * 16 + lr;
        D[(size_t)i * CI_ + j] = (u16)bfr((acc[rt][ct][r] + bias[j]) * alpha);
      }
}

// ---------------- fused V projection (R11, measured-good) ----------------
__global__ __launch_bounds__(256) void proj_v(
    const float* __restrict__ value, const u16* __restrict__ Wv,
    const float* __restrict__ bv, u16* __restrict__ Vo)
{
  __shared__ float Vsf[2][64 * 65];   // 2 x 16.6 KB

  const int bz = blockIdx.z;
  const float* X = value + (size_t)bz * CDIM * HW;
  u16* D = Vo + (size_t)bz * CDIM * HW;

  const int tid = threadIdx.x, wid = tid >> 6, lane = tid & 63;
  const int lr = lane & 15, lg = lane >> 4;
  const int i0 = blockIdx.x * 128 + wid * 32;   // c_out base (wave)
  const int j0 = blockIdx.y * 64;               // m base (block)

  const int srow = tid >> 3;            // 0..31
  const int scol = (tid & 7) * 4;       // + 32*jj, jj 0..1
  uint4 sv[2][2];

#define PVLOAD(T) do { \
    _Pragma("unroll") \
    for (int p = 0; p < 2; ++p) \
      _Pragma("unroll") \
      for (int jj = 0; jj < 2; ++jj) \
        sv[p][jj] = *(const uint4*)(X + (size_t)((T) * 64 + srow + 32 * p) * HW + j0 + scol + 32 * jj); \
  } while (0)
#define PVWRITE(BUF) do { \
    _Pragma("unroll") \
    for (int p = 0; p < 2; ++p) \
      _Pragma("unroll") \
      for (int jj = 0; jj < 2; ++jj) \
        *(uint4*)(&Vsf[BUF][(srow + 32 * p) * 65 + scol + 32 * jj]) = sv[p][jj]; \
  } while (0)

  f32x4 acc[2][4];
#pragma unroll
  for (int rt = 0; rt < 2; ++rt)
#pragma unroll
    for (int ct = 0; ct < 4; ++ct) acc[rt][ct] = (f32x4){0.f, 0.f, 0.f, 0.f};

  PVLOAD(0); PVWRITE(0);
  __syncthreads();

  for (int t = 0; t < 8; ++t) {
    const int par = t & 1;
    if (t + 1 < 8) PVLOAD(t + 1);

#pragma unroll
    for (int kk = 0; kk < 2; ++kk) {
      bf16x8 af[2];
#pragma unroll
      for (int rt = 0; rt < 2; ++rt)
        af[rt] = *(const bf16x8*)(Wv + (size_t)(i0 + rt * 16 + lr) * CDIM + t * 64 + kk * 32 + lg * 8);
#pragma unroll
      for (int ct = 0; ct < 4; ++ct) {
        const float* col = &Vsf[par][(kk * 32 + lg * 8) * 65 + ct * 16 + lr];
        fragu fu;
#pragma unroll
        for (int j = 0; j < 4; ++j)
          fu.w[j] = cvtpk(col[(2 * j) * 65], col[(2 * j + 1) * 65]);
        bf16x8 bf = fu.v;
        acc[0][ct] = MFMA16(af[0], bf, acc[0][ct]);
        acc[1][ct] = MFMA16(af[1], bf, acc[1][ct]);
      }
    }

    if (t + 1 < 8) PVWRITE((t + 1) & 1);
    __syncthreads();
  }

#pragma unroll
  for (int rt = 0; rt < 2; ++rt)
#pragma unroll
    for (int ct = 0; ct < 4; ++ct)
#pragma unroll
      for (int r = 0; r < 4; ++r) {
        int i = i0 + rt * 16 + lg * 4 + r;
        int j = j0 + ct * 16 + lr;
        D[(size_t)i * HW + j] = (u16)bfr(acc[rt][ct][r] + bv[i]);
      }
}

// ---------------- fused flash attention + gamma*attn + value (G3: QK dedup x4 -> x2) ----------------
// Wave = 32 q-rows x 256 c (acc = 8 x f32x16 = 128, same budget as proven kernel).
// Block = 4 waves = 128 q x 256 c; grid = 8b x 32rb x 2ch = 512 blocks, 2 blocks/CU.
// Same proven pieces: MT=64, ONE barrier/tile, GLDS pre-swizzled staging
// (Vs now 256 rows, identical 128B-row chunk involution), T12 pack, exp2 fold.
__global__ __launch_bounds__(256, 2) void flash_attn(
    const u16* __restrict__ Q, const u16* __restrict__ K, const u16* __restrict__ V,
    const float* __restrict__ value, const float* __restrict__ gammap, float* __restrict__ out)
{
  __shared__ u16 Ks[2][64 * 64];     // 2 x 8 KB   [m=64][ci=64], swizzled chunks
  __shared__ u16 Vs[2][256 * 64];    // 2 x 32 KB  [c=256][m=64], swizzled chunks

  const int b  = blockIdx.x & 7;
  const int rb = (blockIdx.x >> 3) & 31;
  const int ch = blockIdx.x >> 8;
  const int tid = threadIdx.x, wid = tid >> 6, lane = tid & 63;
  const int l31 = lane & 31, h = lane >> 5;

  const int n0 = rb * 128 + wid * 32;   // wave q-row base (32 rows)
  const int c0 = ch * 256;              // block c base (256 cols)

  const u16* Qb = Q + (size_t)b * HW * CI_;
  const u16* Kb = K + (size_t)b * HW * CI_;
  const u16* Vb = V + (size_t)b * CDIM * HW + (size_t)c0 * HW;

  // Q B-frags: col n = n0 + l31, k = kk*16 + h*8 + j
  bf16x8 qf[4];
  {
    const u16* qp = Qb + (size_t)(n0 + l31) * CI_ + h * 8;
#pragma unroll
    for (int kk = 0; kk < 4; ++kk) qf[kk] = *(const bf16x8*)(qp + kk * 16);
  }

  f32x16 acc[8];
#pragma unroll
  for (int ct = 0; ct < 8; ++ct)
#pragma unroll
    for (int i = 0; i < 16; ++i) acc[ct][i] = 0.f;
  float lp = 0.f;

  // ---- staging sources (pre-swizzled): lane -> (row = 8-block + lane>>3, chunk = lane&7)
  const int lrow = lane >> 3, lchk = lane & 7;
  const int swz = lchk ^ lrow;
  const u16* kcur = Kb + (size_t)(wid * 16 + lrow) * CI_ + swz * 8;   // wave: 16 K-rows
  const u16* vcur = Vb + (size_t)(wid * 64 + lrow) * HW + swz * 8;    // wave: 64 V-rows
  const int kofs = wid * 16 * 64, vofs = wid * 64 * 64;   // u16 LDS offsets

#define ISSUE(BUF) do { \
    GLDS16(kcur,           &Ks[BUF][kofs]); \
    GLDS16(kcur + 8 * CI_, &Ks[BUF][kofs + 8 * 64]); \
    _Pragma("unroll") \
    for (int j = 0; j < 8; ++j) \
      GLDS16(vcur + (size_t)(8 * j) * HW, &Vs[BUF][vofs + j * 8 * 64]); \
  } while (0)

  ISSUE(0);
  __syncthreads();   // compiler-inserted vmcnt(0) drains the DMA

  for (int t = 0; t < NTIL; ++t) {
    const int par = t & 1;
    if (t + 1 < NTIL) {            // issue next-tile DMA; drains at this tile's end barrier
      kcur += MT * CI_;
      vcur += MT;
      ISSUE(par ^ 1);
    }

#pragma unroll
    for (int s = 0; s < 2; ++s) {  // m-strip of 32 within the 64-m tile
      // K A-frags: row m = s*32 + l31, chunk j = 2kk+h, swizzled by (m&7)==(l31&7)
      bf16x8 kf[4];
#pragma unroll
      for (int kk = 0; kk < 4; ++kk)
        kf[kk] = *(const bf16x8*)(&Ks[par][(s * 32 + l31) * 64 + (((2 * kk + h) ^ (l31 & 7)) << 3)]);

      // QK (single ng = wave's 32 rows): S^T strip 32m x 32n
      f32x16 st;
#pragma unroll
      for (int i = 0; i < 16; ++i) st[i] = 0.f;
#pragma unroll
      for (int kk = 0; kk < 4; ++kk)
        st = __builtin_amdgcn_mfma_f32_32x32x16_bf16(kf[kk], qf[kk], st, 0, 0, 0);

      // P = exp2(S) (log2e pre-folded); row-sum partial
      float p[16]; float rs = 0.f;
#pragma unroll
      for (int r = 0; r < 16; ++r) { p[r] = hexp2(st[r]); rs += p[r]; }
      lp += rs;

      // T12 pack: quads m(r) = (r&3) + 8*(r>>2) + 4h (within strip)
      u32 qa0 = cvtpk(p[0],  p[1]),  qa1 = cvtpk(p[2],  p[3]);   // m 4h+0..3
      u32 qb0 = cvtpk(p[4],  p[5]),  qb1 = cvtpk(p[6],  p[7]);   // m 8+4h+0..3
      u32 qc0 = cvtpk(p[8],  p[9]),  qc1 = cvtpk(p[10], p[11]);  // m 16+4h+0..3
      u32 qd0 = cvtpk(p[12], p[13]), qd1 = cvtpk(p[14], p[15]);  // m 24+4h+0..3
      asm("v_permlane32_swap_b32 %0, %1" : "+v"(qa0), "+v"(qb0));
      asm("v_permlane32_swap_b32 %0, %1" : "+v"(qa1), "+v"(qb1));
      asm("v_permlane32_swap_b32 %0, %1" : "+v"(qc0), "+v"(qd0));
      asm("v_permlane32_swap_b32 %0, %1" : "+v"(qc1), "+v"(qd1));
      bf16x8 pa[2];
      fragu f0; f0.w[0] = qa0; f0.w[1] = qa1; f0.w[2] = qb0; f0.w[3] = qb1;
      pa[0] = f0.v;
      fragu f1; f1.w[0] = qc0; f1.w[1] = qc1; f1.w[2] = qd0; f1.w[3] = qd1;
      pa[1] = f1.v;

      // PV for this strip over the wave's 256 c: V chunk j = 4s + 2kkl + h
      __builtin_amdgcn_s_setprio(1);
#pragma unroll
      for (int ct = 0; ct < 8; ++ct)
#pragma unroll
        for (int kkl = 0; kkl < 2; ++kkl) {
          bf16x8 vf = *(const bf16x8*)(&Vs[par][(ct * 32 + l31) * 64 + (((4 * s + 2 * kkl + h) ^ (l31 & 7)) << 3)]);
          acc[ct] = __builtin_amdgcn_mfma_f32_32x32x16_bf16(vf, pa[kkl], acc[ct], 0, 0, 0);
        }
      __builtin_amdgcn_s_setprio(0);
    }

    __syncthreads();   // single barrier: drains next-tile DMA + fences dbuf parity
  }

  // ---- epilogue: per-wave LDS transpose so value/out stay coalesced ----
  __syncthreads();   // everyone done with Ks/Vs; reuse as scratch
  float* Tls = (float*)((char*)&Vs[0][0] + wid * 4352);  // 32c x 33n f32 per wave
  const float g = gammap[0];
  const float ls = lp + __shfl_xor(lp, 32);
  const float ri = g / ls;                    // lane's n = l31
  const size_t obase = (size_t)b * CDIM * HW;
#pragma unroll
  for (int ct = 0; ct < 8; ++ct) {
    // write: Tls[c_local][n_local]
#pragma unroll
    for (int r = 0; r < 16; ++r) {
      int cc = (r & 3) + 8 * (r >> 2) + 4 * h;
      Tls[cc * 33 + l31] = acc[ct][r] * ri;
    }
    // read coalesced: lane -> c = l31, n = 2p + h
#pragma unroll
    for (int p = 0; p < 16; ++p) {
      float v = Tls[l31 * 33 + 2 * p + h];
      int n = n0 + 2 * p + h;
      int c = c0 + ct * 32 + l31;
      size_t idx = obase + (size_t)n * CDIM + c;
      out[idx] = v + value[idx];
    }
    // Tls reused per ct by the same wave; no cross-wave sharing -> wave-coherent
  }
}

extern "C" void kernel_launch(void* const* d_in, const int* in_sizes, int n_in,
                              void* d_out, int out_size, void* d_ws, size_t ws_size,
                              hipStream_t stream) {
  const float* query = (const float*)d_in[0];
  const float* key   = (const float*)d_in[1];
  const float* value = (const float*)d_in[2];
  const float* Wq    = (const float*)d_in[3];
  const float* bq    = (const float*)d_in[4];
  const float* Wk    = (const float*)d_in[5];
  const float* bk    = (const float*)d_in[6];
  const float* Wv    = (const float*)d_in[7];
  const float* bv    = (const float*)d_in[8];
  const float* gamma = (const float*)d_in[9];

  char* ws = (char*)d_ws;
  u16* Qb  = (u16*)(ws);               //  4,194,304 B  [B,HW,CI]
  u16* Kb  = (u16*)(ws + 4194304);     //  4,194,304 B  [B,HW,CI]
  u16* Vb  = (u16*)(ws + 8388608);     // 33,554,432 B  [B,C,HW] V^T
  u16* WQb = (u16*)(ws + 41943040);    //     65,536 B
  u16* WKb = (u16*)(ws + 42008576);    //     65,536 B
  u16* WVb = (u16*)(ws + 42074112);    //    524,288 B

  // 1) weight casts
  cast3<<<(CDIM * CDIM) / 256, 256, 0, stream>>>(Wq, Wk, Wv, WQb, WKb, WVb);

  // 2) Q and K projections with fused transpose+cast (z<8: Q, z>=8: K)
  proj_qk<<<dim3(HW / 128, 1, 16), 256, 0, stream>>>(
      query, key, WQb, WKb, bq, bk, Qb, Kb);

  // 3) V^T projection with fused transpose+cast -> [B, C, HW]
  proj_v<<<dim3(CDIM / 128, HW / 64, B_), 256, 0, stream>>>(
      value, WVb, bv, Vb);

  // 4) fused flash attention + epilogue (G3 geometry)
  flash_attn<<<512, 256, 0, stream>>>(Qb, Kb, Vb, value, gamma, (float*)d_out);
}

// Round 14
// 212.650 us; speedup vs baseline: 1.5721x; 1.2740x over previous
//
#include <hip/hip_runtime.h>
#include <hip/hip_bf16.h>
#include <math.h>

// Problem constants
#define B_    8
#define CDIM  512
#define HW    4096
#define CI_   64
#define MT    64            // kv rows per tile
#define NTIL  (HW/MT)       // 64 tiles

typedef __attribute__((ext_vector_type(8))) short bf16x8;
typedef __attribute__((ext_vector_type(8))) int   i32x8;
typedef __attribute__((ext_vector_type(4))) float f32x4;
typedef __attribute__((ext_vector_type(16))) float f32x16;
typedef unsigned short u16;
typedef unsigned char  u8;
typedef unsigned int   u32;

union fragu { bf16x8 v; u32 w[4]; };

// fp32 -> bf16 bits with RNE rounding
__device__ __forceinline__ u32 bfr(float f) {
  u32 x = __float_as_uint(f);
  return (x + 0x7fffu + ((x >> 16) & 1u)) >> 16;
}
// packed 2xf32 -> bf16x2 (RNE) via HW instruction
__device__ __forceinline__ u32 cvtpk(float a, float b) {
  u32 r;
  asm("v_cvt_pk_bf16_f32 %0, %1, %2" : "=v"(r) : "v"(a), "v"(b));
  return r;
}
// 4xf32 -> 4x e4m3fn packed in one u32 (RNE)
__device__ __forceinline__ u32 pk4fp8(float a, float b, float c, float d) {
  u32 w;
  asm("v_cvt_pk_fp8_f32 %0, %1, %2" : "=v"(w) : "v"(a), "v"(b));
  asm("v_cvt_pk_fp8_f32 %0, %1, %2 op_sel:[0,0,1]" : "+v"(w) : "v"(c), "v"(d));
  return w;
}
// single f32 -> e4m3fn byte
__device__ __forceinline__ u32 f8byte(float v) {
  u32 w;
  asm("v_cvt_pk_fp8_f32 %0, %1, %2" : "=v"(w) : "v"(v), "v"(v));
  return w & 0xffu;
}
// raw v_exp_f32 = exp2 (log2e is pre-folded into Q's projection scale)
__device__ __forceinline__ float hexp2(float x) {
  float r;
  asm("v_exp_f32 %0, %1" : "=v"(r) : "v"(x));
  return r;
}

// global -> LDS direct DMA, 16B/lane (dest = wave-uniform base + lane*16, linear)
typedef const __attribute__((address_space(1))) void g1cv;
typedef __attribute__((address_space(3))) void l3v;
#define GLDS16(g, l) __builtin_amdgcn_global_load_lds((g1cv*)(g), (l3v*)(l), 16, 0, 0)

#define MFMA16(a, b, c) __builtin_amdgcn_mfma_f32_16x16x32_bf16(a, b, c, 0, 0, 0)

// ---------------- cast fp32 -> bf16 for the three weight tensors ----------------
__global__ void cast3(const float* __restrict__ wq, const float* __restrict__ wk,
                      const float* __restrict__ wv, u16* __restrict__ oq,
                      u16* __restrict__ ok, u16* __restrict__ ov) {
  int i = blockIdx.x * 256 + threadIdx.x;
  if (i < CI_ * CDIM) { oq[i] = (u16)bfr(wq[i]); ok[i] = (u16)bfr(wk[i]); }
  ov[i] = (u16)bfr(wv[i]);   // grid sized to CDIM*CDIM
}

// ---------------- fused Q/K projection (R11, measured-good, unchanged) ----------------
__global__ __launch_bounds__(256) void proj_qk(
    const float* __restrict__ query, const float* __restrict__ key,
    const u16* __restrict__ Wq, const u16* __restrict__ Wk,
    const float* __restrict__ bq, const float* __restrict__ bk,
    u16* __restrict__ Qo, u16* __restrict__ Ko)
{
  __shared__ float Xs[2][64 * 129];   // 2 x 33 KB

  const int z = blockIdx.z;
  const bool isq = z < 8;
  const int bz = isq ? z : z - 8;
  const float* X = (isq ? query : key) + (size_t)bz * CDIM * HW;
  const u16* W = isq ? Wq : Wk;
  const float* bias = isq ? bq : bk;
  const float alpha = isq ? 0.125f * 1.44269504f : 1.0f;
  u16* D = (isq ? Qo : Ko) + (size_t)bz * HW * CI_;

  const int tid = threadIdx.x, wid = tid >> 6, lane = tid & 63;
  const int lr = lane & 15, lg = lane >> 4;
  const int n0 = blockIdx.x * 128;

  const int srow = tid >> 3;            // 0..31
  const int scol = (tid & 7) * 4;       // f32 col base; + 32*jj
  uint4 sx[2][4];

#define PQLOAD(T) do { \
    _Pragma("unroll") \
    for (int p = 0; p < 2; ++p) \
      _Pragma("unroll") \
      for (int jj = 0; jj < 4; ++jj) \
        sx[p][jj] = *(const uint4*)(X + (size_t)((T) * 64 + srow + 32 * p) * HW + n0 + scol + 32 * jj); \
  } while (0)
#define PQWRITE(BUF) do { \
    _Pragma("unroll") \
    for (int p = 0; p < 2; ++p) \
      _Pragma("unroll") \
      for (int jj = 0; jj < 4; ++jj) \
        *(uint4*)(&Xs[BUF][(srow + 32 * p) * 129 + scol + 32 * jj]) = sx[p][jj]; \
  } while (0)

  f32x4 acc[2][4];
#pragma unroll
  for (int rt = 0; rt < 2; ++rt)
#pragma unroll
    for (int ct = 0; ct < 4; ++ct) acc[rt][ct] = (f32x4){0.f, 0.f, 0.f, 0.f};

  PQLOAD(0); PQWRITE(0);
  __syncthreads();

  for (int t = 0; t < 8; ++t) {
    const int par = t & 1;
    if (t + 1 < 8) PQLOAD(t + 1);

#pragma unroll
    for (int kk = 0; kk < 2; ++kk) {
      bf16x8 af[2];
#pragma unroll
      for (int rt = 0; rt < 2; ++rt) {
        const float* col = &Xs[par][(kk * 32 + lg * 8) * 129 + wid * 32 + rt * 16 + lr];
        fragu fu;
#pragma unroll
        for (int j = 0; j < 4; ++j)
          fu.w[j] = cvtpk(col[(2 * j) * 129], col[(2 * j + 1) * 129]);
        af[rt] = fu.v;
      }
#pragma unroll
      for (int ct = 0; ct < 4; ++ct) {
        bf16x8 bf = *(const bf16x8*)(W + (size_t)(ct * 16 + lr) * CDIM + t * 64 + kk * 32 + lg * 8);
        acc[0][ct] = MFMA16(af[0], bf, acc[0][ct]);
        acc[1][ct] = MFMA16(af[1], bf, acc[1][ct]);
      }
    }

    if (t + 1 < 8) PQWRITE((t + 1) & 1);
    __syncthreads();
  }

#pragma unroll
  for (int rt = 0; rt < 2; ++rt)
#pragma unroll
    for (int ct = 0; ct < 4; ++ct)
#pragma unroll
      for (int r = 0; r < 4; ++r) {
        int i = n0 + wid * 32 + rt * 16 + lg * 4 + r;
        int j = ct * 16 + lr;
        D[(size_t)i * CI_ + j] = (u16)bfr((acc[rt][ct][r] + bias[j]) * alpha);
      }
}

// ---------------- fused V projection -> e4m3fn output [B, C, HW] ----------------
__global__ __launch_bounds__(256) void proj_v(
    const float* __restrict__ value, const u16* __restrict__ Wv,
    const float* __restrict__ bv, u8* __restrict__ Vo)
{
  __shared__ float Vsf[2][64 * 65];   // 2 x 16.6 KB

  const int bz = blockIdx.z;
  const float* X = value + (size_t)bz * CDIM * HW;
  u8* D = Vo + (size_t)bz * CDIM * HW;

  const int tid = threadIdx.x, wid = tid >> 6, lane = tid & 63;
  const int lr = lane & 15, lg = lane >> 4;
  const int i0 = blockIdx.x * 128 + wid * 32;   // c_out base (wave)
  const int j0 = blockIdx.y * 64;               // m base (block)

  const int srow = tid >> 3;            // 0..31
  const int scol = (tid & 7) * 4;       // + 32*jj, jj 0..1
  uint4 sv[2][2];

#define PVLOAD(T) do { \
    _Pragma("unroll") \
    for (int p = 0; p < 2; ++p) \
      _Pragma("unroll") \
      for (int jj = 0; jj < 2; ++jj) \
        sv[p][jj] = *(const uint4*)(X + (size_t)((T) * 64 + srow + 32 * p) * HW + j0 + scol + 32 * jj); \
  } while (0)
#define PVWRITE(BUF) do { \
    _Pragma("unroll") \
    for (int p = 0; p < 2; ++p) \
      _Pragma("unroll") \
      for (int jj = 0; jj < 2; ++jj) \
        *(uint4*)(&Vsf[BUF][(srow + 32 * p) * 65 + scol + 32 * jj]) = sv[p][jj]; \
  } while (0)

  f32x4 acc[2][4];
#pragma unroll
  for (int rt = 0; rt < 2; ++rt)
#pragma unroll
    for (int ct = 0; ct < 4; ++ct) acc[rt][ct] = (f32x4){0.f, 0.f, 0.f, 0.f};

  PVLOAD(0); PVWRITE(0);
  __syncthreads();

  for (int t = 0; t < 8; ++t) {
    const int par = t & 1;
    if (t + 1 < 8) PVLOAD(t + 1);

#pragma unroll
    for (int kk = 0; kk < 2; ++kk) {
      bf16x8 af[2];
#pragma unroll
      for (int rt = 0; rt < 2; ++rt)
        af[rt] = *(const bf16x8*)(Wv + (size_t)(i0 + rt * 16 + lr) * CDIM + t * 64 + kk * 32 + lg * 8);
#pragma unroll
      for (int ct = 0; ct < 4; ++ct) {
        const float* col = &Vsf[par][(kk * 32 + lg * 8) * 65 + ct * 16 + lr];
        fragu fu;
#pragma unroll
        for (int j = 0; j < 4; ++j)
          fu.w[j] = cvtpk(col[(2 * j) * 65], col[(2 * j + 1) * 65]);
        bf16x8 bf = fu.v;
        acc[0][ct] = MFMA16(af[0], bf, acc[0][ct]);
        acc[1][ct] = MFMA16(af[1], bf, acc[1][ct]);
      }
    }

    if (t + 1 < 8) PVWRITE((t + 1) & 1);
    __syncthreads();
  }

#pragma unroll
  for (int rt = 0; rt < 2; ++rt)
#pragma unroll
    for (int ct = 0; ct < 4; ++ct)
#pragma unroll
      for (int r = 0; r < 4; ++r) {
        int i = i0 + rt * 16 + lg * 4 + r;
        int j = j0 + ct * 16 + lr;
        D[(size_t)i * HW + j] = (u8)f8byte(acc[rt][ct][r] + bv[i]);
      }
}

// ---------------- fused flash attention: bf16 QK + FP8 (e4m3, K=64 MX) PV ----------------
// G3 geometry (R13, measured 182.7us): wave = 32q x 256c, block = 128q x 256c,
// grid = 8b x 32rb x 2ch = 512 blocks, 2 blocks/CU, one barrier/tile.
// New: V staged as fp8 [256c][64B rows] (GLDS pre-swizzled, slot ^= (row>>1)&3);
// P packed to fp8 in-register (pk4fp8 + 4 permlane32_swap -> one 32B B-frag);
// PV = ONE mfma_scale_f32_32x32x64_f8f6f4 per ct (identity scales = e8m0 127).
__global__ __launch_bounds__(256, 2) void flash_attn(
    const u16* __restrict__ Q, const u16* __restrict__ K, const u8* __restrict__ V,
    const float* __restrict__ value, const float* __restrict__ gammap, float* __restrict__ out)
{
  __shared__ u16 Ks[2][64 * 64];     // 2 x 8 KB   bf16 K [m=64][ci=64], 8-chunk swizzle
  __shared__ u8  Vs[2][256 * 64];    // 2 x 16 KB  fp8 V [c=256][m=64B], 4-slot swizzle

  const int b  = blockIdx.x & 7;
  const int rb = (blockIdx.x >> 3) & 31;
  const int ch = blockIdx.x >> 8;
  const int tid = threadIdx.x, wid = tid >> 6, lane = tid & 63;
  const int l31 = lane & 31, h = lane >> 5;

  const int n0 = rb * 128 + wid * 32;   // wave q-row base (32 rows)
  const int c0 = ch * 256;              // block c base (256 cols)

  const u16* Qb = Q + (size_t)b * HW * CI_;
  const u16* Kb = K + (size_t)b * HW * CI_;
  const u8*  Vb = V + (size_t)b * CDIM * HW + (size_t)c0 * HW;

  // Q B-frags (bf16): col n = n0 + l31, k = kk*16 + h*8 + j
  bf16x8 qf[4];
  {
    const u16* qp = Qb + (size_t)(n0 + l31) * CI_ + h * 8;
#pragma unroll
    for (int kk = 0; kk < 4; ++kk) qf[kk] = *(const bf16x8*)(qp + kk * 16);
  }

  f32x16 acc[8];
#pragma unroll
  for (int ct = 0; ct < 8; ++ct)
#pragma unroll
    for (int i = 0; i < 16; ++i) acc[ct][i] = 0.f;
  float lp = 0.f;

  // ---- staging sources (pre-swizzled) ----
  // K (bf16, 8 chunks/row): lane -> row lane>>3, chunk lane&7; involution chunk ^= row&7
  const int klrow = lane >> 3;
  const int kswz = (lane & 7) ^ klrow;
  const u16* kcur = Kb + (size_t)(wid * 16 + klrow) * CI_ + kswz * 8;
  const int kofs = wid * 16 * 64;       // u16 offset
  // V (fp8, 4 slots/row): lane -> row lane>>2, slot lane&3; involution slot ^= (row>>1)&3
  const int vlrow = lane >> 2;
  const int vswz = (lane & 3) ^ ((lane >> 3) & 3);
  const u8* vcur = Vb + (size_t)(wid * 64 + vlrow) * HW + vswz * 16;
  const int vofs = wid * 64 * 64;       // byte offset

#define ISSUE(BUF) do { \
    GLDS16(kcur,           &Ks[BUF][kofs]); \
    GLDS16(kcur + 8 * CI_, &Ks[BUF][kofs + 8 * 64]); \
    _Pragma("unroll") \
    for (int it = 0; it < 4; ++it) \
      GLDS16(vcur + (size_t)(16 * it) * HW, &Vs[BUF][vofs + it * 16 * 64]); \
  } while (0)

  ISSUE(0);
  __syncthreads();   // compiler-inserted vmcnt(0) drains the DMA

  const int cswz = (l31 >> 1) & 3;   // V read-slot swizzle for row c = ct*32 + l31

  for (int t = 0; t < NTIL; ++t) {
    const int par = t & 1;
    if (t + 1 < NTIL) {            // issue next-tile DMA; drains at this tile's end barrier
      kcur += MT * CI_;
      vcur += MT;
      ISSUE(par ^ 1);
    }

    // ---- QK both strips (bf16): S^T[strip m 32][n 32] ----
    f32x16 st0, st1;
#pragma unroll
    for (int i = 0; i < 16; ++i) { st0[i] = 0.f; st1[i] = 0.f; }
#pragma unroll
    for (int kk = 0; kk < 4; ++kk) {
      bf16x8 kf0 = *(const bf16x8*)(&Ks[par][(l31) * 64 + (((2 * kk + h) ^ (l31 & 7)) << 3)]);
      bf16x8 kf1 = *(const bf16x8*)(&Ks[par][(32 + l31) * 64 + (((2 * kk + h) ^ (l31 & 7)) << 3)]);
      st0 = __builtin_amdgcn_mfma_f32_32x32x16_bf16(kf0, qf[kk], st0, 0, 0, 0);
      st1 = __builtin_amdgcn_mfma_f32_32x32x16_bf16(kf1, qf[kk], st1, 0, 0, 0);
    }

    // ---- P = exp2(S); pack to fp8; permlane-swap into one K=64 B-frag ----
    float p0[16], p1[16];
    float rs = 0.f;
#pragma unroll
    for (int r = 0; r < 16; ++r) { p0[r] = hexp2(st0[r]); rs += p0[r]; }
#pragma unroll
    for (int r = 0; r < 16; ++r) { p1[r] = hexp2(st1[r]); rs += p1[r]; }
    lp += rs;

    i32x8 pfrag;
#pragma unroll
    for (int g = 0; g < 4; ++g) {
      // word_s_g = fp8 x4 of m = s*32 + 8g + 4h + 0..3
      u32 w0 = pk4fp8(p0[4 * g], p0[4 * g + 1], p0[4 * g + 2], p0[4 * g + 3]);
      u32 w1 = pk4fp8(p1[4 * g], p1[4 * g + 1], p1[4 * g + 2], p1[4 * g + 3]);
      // h=0: w0 own (m 8g+0..3), w1 <- partner strip0 (m 8g+4..7)
      // h=1: w0 <- partner strip1 (m 32+8g+0..3), w1 own (m 32+8g+4..7)
      asm("v_permlane32_swap_b32 %0, %1" : "+v"(w0), "+v"(w1));
      pfrag[2 * g]     = (int)w0;
      pfrag[2 * g + 1] = (int)w1;
    }

    // ---- PV: one K=64 fp8 MFMA per ct (scales = 1.0) ----
    __builtin_amdgcn_s_setprio(1);
#pragma unroll
    for (int ct = 0; ct < 8; ++ct) {
      const u8* vb = &Vs[par][(ct * 32 + l31) * 64];
      uint4 lo = *(const uint4*)(vb + (((2 * h)     ^ cswz) << 4));
      uint4 hi = *(const uint4*)(vb + (((2 * h + 1) ^ cswz) << 4));
      i32x8 vfrag;
      vfrag[0] = (int)lo.x; vfrag[1] = (int)lo.y; vfrag[2] = (int)lo.z; vfrag[3] = (int)lo.w;
      vfrag[4] = (int)hi.x; vfrag[5] = (int)hi.y; vfrag[6] = (int)hi.z; vfrag[7] = (int)hi.w;
      acc[ct] = __builtin_amdgcn_mfma_scale_f32_32x32x64_f8f6f4(
                    vfrag, pfrag, acc[ct], 0, 0, 0, 127, 0, 127);
    }
    __builtin_amdgcn_s_setprio(0);

    __syncthreads();   // single barrier: drains next-tile DMA + fences dbuf parity
  }

  // ---- epilogue: per-wave LDS transpose so value/out stay coalesced ----
  __syncthreads();   // everyone done with Ks/Vs; reuse as scratch
  float* Tls = (float*)((char*)&Vs[0][0] + wid * 4352);  // 32c x 33n f32 per wave
  const float g = gammap[0];
  const float ls = lp + __shfl_xor(lp, 32);
  const float ri = g / ls;                    // lane's n = l31
  const size_t obase = (size_t)b * CDIM * HW;
#pragma unroll
  for (int ct = 0; ct < 8; ++ct) {
    // write: Tls[c_local][n_local]
#pragma unroll
    for (int r = 0; r < 16; ++r) {
      int cc = (r & 3) + 8 * (r >> 2) + 4 * h;
      Tls[cc * 33 + l31] = acc[ct][r] * ri;
    }
    // read coalesced: lane -> c = l31, n = 2p + h
#pragma unroll
    for (int p = 0; p < 16; ++p) {
      float v = Tls[l31 * 33 + 2 * p + h];
      int n = n0 + 2 * p + h;
      int c = c0 + ct * 32 + l31;
      size_t idx = obase + (size_t)n * CDIM + c;
      out[idx] = v + value[idx];
    }
  }
}

extern "C" void kernel_launch(void* const* d_in, const int* in_sizes, int n_in,
                              void* d_out, int out_size, void* d_ws, size_t ws_size,
                              hipStream_t stream) {
  const float* query = (const float*)d_in[0];
  const float* key   = (const float*)d_in[1];
  const float* value = (const float*)d_in[2];
  const float* Wq    = (const float*)d_in[3];
  const float* bq    = (const float*)d_in[4];
  const float* Wk    = (const float*)d_in[5];
  const float* bk    = (const float*)d_in[6];
  const float* Wv    = (const float*)d_in[7];
  const float* bv    = (const float*)d_in[8];
  const float* gamma = (const float*)d_in[9];

  char* ws = (char*)d_ws;
  u16* Qb  = (u16*)(ws);               //  4,194,304 B  [B,HW,CI] bf16
  u16* Kb  = (u16*)(ws + 4194304);     //  4,194,304 B  [B,HW,CI] bf16
  u8*  Vb  = (u8*)(ws + 8388608);      // 16,777,216 B  [B,C,HW] e4m3fn V^T
  u16* WQb = (u16*)(ws + 25165824);    //     65,536 B
  u16* WKb = (u16*)(ws + 25231360);    //     65,536 B
  u16* WVb = (u16*)(ws + 25296896);    //    524,288 B

  // 1) weight casts
  cast3<<<(CDIM * CDIM) / 256, 256, 0, stream>>>(Wq, Wk, Wv, WQb, WKb, WVb);

  // 2) Q and K projections with fused transpose+cast (z<8: Q, z>=8: K)
  proj_qk<<<dim3(HW / 128, 1, 16), 256, 0, stream>>>(
      query, key, WQb, WKb, bq, bk, Qb, Kb);

  // 3) V^T projection with fused transpose+cast -> [B, C, HW] fp8
  proj_v<<<dim3(CDIM / 128, HW / 64, B_), 256, 0, stream>>>(
      value, WVb, bv, Vb);

  // 4) fused flash attention + epilogue (fp8 PV)
  flash_attn<<<512, 256, 0, stream>>>(Qb, Kb, Vb, value, gamma, (float*)d_out);
}

// Round 15
// 195.976 us; speedup vs baseline: 1.7058x; 1.0851x over previous
//
#include <hip/hip_runtime.h>
#include <hip/hip_bf16.h>
#include <math.h>

// Problem constants
#define B_    8
#define CDIM  512
#define HW    4096
#define CI_   64
#define MT    64            // kv rows per tile
#define NTIL  (HW/MT)       // 64 tiles

typedef __attribute__((ext_vector_type(8))) short bf16x8;
typedef __attribute__((ext_vector_type(8))) int   i32x8;
typedef __attribute__((ext_vector_type(4))) float f32x4;
typedef __attribute__((ext_vector_type(16))) float f32x16;
typedef unsigned short u16;
typedef unsigned char  u8;
typedef unsigned int   u32;

union fragu { bf16x8 v; u32 w[4]; };

// fp32 -> bf16 bits with RNE rounding
__device__ __forceinline__ u32 bfr(float f) {
  u32 x = __float_as_uint(f);
  return (x + 0x7fffu + ((x >> 16) & 1u)) >> 16;
}
// packed 2xf32 -> bf16x2 (RNE) via HW instruction
__device__ __forceinline__ u32 cvtpk(float a, float b) {
  u32 r;
  asm("v_cvt_pk_bf16_f32 %0, %1, %2" : "=v"(r) : "v"(a), "v"(b));
  return r;
}
// 4xf32 -> 4x e4m3fn packed in one u32 (RNE)
__device__ __forceinline__ u32 pk4fp8(float a, float b, float c, float d) {
  u32 w;
  asm("v_cvt_pk_fp8_f32 %0, %1, %2" : "=v"(w) : "v"(a), "v"(b));
  asm("v_cvt_pk_fp8_f32 %0, %1, %2 op_sel:[0,0,1]" : "+v"(w) : "v"(c), "v"(d));
  return w;
}
// single f32 -> e4m3fn byte
__device__ __forceinline__ u32 f8byte(float v) {
  u32 w;
  asm("v_cvt_pk_fp8_f32 %0, %1, %2" : "=v"(w) : "v"(v), "v"(v));
  return w & 0xffu;
}
// raw v_exp_f32 = exp2 (log2e is pre-folded into Q's projection scale)
__device__ __forceinline__ float hexp2(float x) {
  float r;
  asm("v_exp_f32 %0, %1" : "=v"(r) : "v"(x));
  return r;
}

// global -> LDS direct DMA, 16B/lane (dest = wave-uniform base + lane*16, linear)
typedef const __attribute__((address_space(1))) void g1cv;
typedef __attribute__((address_space(3))) void l3v;
#define GLDS16(g, l) __builtin_amdgcn_global_load_lds((g1cv*)(g), (l3v*)(l), 16, 0, 0)

#define MFMA16(a, b, c) __builtin_amdgcn_mfma_f32_16x16x32_bf16(a, b, c, 0, 0, 0)

// ---------------- cast fp32 -> bf16 for the three weight tensors ----------------
__global__ void cast3(const float* __restrict__ wq, const float* __restrict__ wk,
                      const float* __restrict__ wv, u16* __restrict__ oq,
                      u16* __restrict__ ok, u16* __restrict__ ov) {
  int i = blockIdx.x * 256 + threadIdx.x;
  if (i < CI_ * CDIM) { oq[i] = (u16)bfr(wq[i]); ok[i] = (u16)bfr(wk[i]); }
  ov[i] = (u16)bfr(wv[i]);   // grid sized to CDIM*CDIM
}

// ---------------- fused Q/K projection -> e4m3fn outputs [HW, 64B] ----------------
// z<8: Q from query (alpha = 0.125*log2e folded); z>=8: K from key.
__global__ __launch_bounds__(256) void proj_qk(
    const float* __restrict__ query, const float* __restrict__ key,
    const u16* __restrict__ Wq, const u16* __restrict__ Wk,
    const float* __restrict__ bq, const float* __restrict__ bk,
    u8* __restrict__ Qo, u8* __restrict__ Ko)
{
  __shared__ float Xs[2][64 * 129];   // 2 x 33 KB

  const int z = blockIdx.z;
  const bool isq = z < 8;
  const int bz = isq ? z : z - 8;
  const float* X = (isq ? query : key) + (size_t)bz * CDIM * HW;
  const u16* W = isq ? Wq : Wk;
  const float* bias = isq ? bq : bk;
  const float alpha = isq ? 0.125f * 1.44269504f : 1.0f;
  u8* D = (isq ? Qo : Ko) + (size_t)bz * HW * CI_;

  const int tid = threadIdx.x, wid = tid >> 6, lane = tid & 63;
  const int lr = lane & 15, lg = lane >> 4;
  const int n0 = blockIdx.x * 128;

  const int srow = tid >> 3;            // 0..31
  const int scol = (tid & 7) * 4;       // f32 col base; + 32*jj
  uint4 sx[2][4];

#define PQLOAD(T) do { \
    _Pragma("unroll") \
    for (int p = 0; p < 2; ++p) \
      _Pragma("unroll") \
      for (int jj = 0; jj < 4; ++jj) \
        sx[p][jj] = *(const uint4*)(X + (size_t)((T) * 64 + srow + 32 * p) * HW + n0 + scol + 32 * jj); \
  } while (0)
#define PQWRITE(BUF) do { \
    _Pragma("unroll") \
    for (int p = 0; p < 2; ++p) \
      _Pragma("unroll") \
      for (int jj = 0; jj < 4; ++jj) \
        *(uint4*)(&Xs[BUF][(srow + 32 * p) * 129 + scol + 32 * jj]) = sx[p][jj]; \
  } while (0)

  f32x4 acc[2][4];
#pragma unroll
  for (int rt = 0; rt < 2; ++rt)
#pragma unroll
    for (int ct = 0; ct < 4; ++ct) acc[rt][ct] = (f32x4){0.f, 0.f, 0.f, 0.f};

  PQLOAD(0); PQWRITE(0);
  __syncthreads();

  for (int t = 0; t < 8; ++t) {
    const int par = t & 1;
    if (t + 1 < 8) PQLOAD(t + 1);

#pragma unroll
    for (int kk = 0; kk < 2; ++kk) {
      bf16x8 af[2];
#pragma unroll
      for (int rt = 0; rt < 2; ++rt) {
        const float* col = &Xs[par][(kk * 32 + lg * 8) * 129 + wid * 32 + rt * 16 + lr];
        fragu fu;
#pragma unroll
        for (int j = 0; j < 4; ++j)
          fu.w[j] = cvtpk(col[(2 * j) * 129], col[(2 * j + 1) * 129]);
        af[rt] = fu.v;
      }
#pragma unroll
      for (int ct = 0; ct < 4; ++ct) {
        bf16x8 bf = *(const bf16x8*)(W + (size_t)(ct * 16 + lr) * CDIM + t * 64 + kk * 32 + lg * 8);
        acc[0][ct] = MFMA16(af[0], bf, acc[0][ct]);
        acc[1][ct] = MFMA16(af[1], bf, acc[1][ct]);
      }
    }

    if (t + 1 < 8) PQWRITE((t + 1) & 1);
    __syncthreads();
  }

#pragma unroll
  for (int rt = 0; rt < 2; ++rt)
#pragma unroll
    for (int ct = 0; ct < 4; ++ct)
#pragma unroll
      for (int r = 0; r < 4; ++r) {
        int i = n0 + wid * 32 + rt * 16 + lg * 4 + r;
        int j = ct * 16 + lr;
        D[(size_t)i * CI_ + j] = (u8)f8byte((acc[rt][ct][r] + bias[j]) * alpha);
      }
}

// ---------------- fused V projection -> e4m3fn output [B, C, HW] (R14, measured-good) ----------------
__global__ __launch_bounds__(256) void proj_v(
    const float* __restrict__ value, const u16* __restrict__ Wv,
    const float* __restrict__ bv, u8* __restrict__ Vo)
{
  __shared__ float Vsf[2][64 * 65];   // 2 x 16.6 KB

  const int bz = blockIdx.z;
  const float* X = value + (size_t)bz * CDIM * HW;
  u8* D = Vo + (size_t)bz * CDIM * HW;

  const int tid = threadIdx.x, wid = tid >> 6, lane = tid & 63;
  const int lr = lane & 15, lg = lane >> 4;
  const int i0 = blockIdx.x * 128 + wid * 32;   // c_out base (wave)
  const int j0 = blockIdx.y * 64;               // m base (block)

  const int srow = tid >> 3;            // 0..31
  const int scol = (tid & 7) * 4;       // + 32*jj, jj 0..1
  uint4 sv[2][2];

#define PVLOAD(T) do { \
    _Pragma("unroll") \
    for (int p = 0; p < 2; ++p) \
      _Pragma("unroll") \
      for (int jj = 0; jj < 2; ++jj) \
        sv[p][jj] = *(const uint4*)(X + (size_t)((T) * 64 + srow + 32 * p) * HW + j0 + scol + 32 * jj); \
  } while (0)
#define PVWRITE(BUF) do { \
    _Pragma("unroll") \
    for (int p = 0; p < 2; ++p) \
      _Pragma("unroll") \
      for (int jj = 0; jj < 2; ++jj) \
        *(uint4*)(&Vsf[BUF][(srow + 32 * p) * 65 + scol + 32 * jj]) = sv[p][jj]; \
  } while (0)

  f32x4 acc[2][4];
#pragma unroll
  for (int rt = 0; rt < 2; ++rt)
#pragma unroll
    for (int ct = 0; ct < 4; ++ct) acc[rt][ct] = (f32x4){0.f, 0.f, 0.f, 0.f};

  PVLOAD(0); PVWRITE(0);
  __syncthreads();

  for (int t = 0; t < 8; ++t) {
    const int par = t & 1;
    if (t + 1 < 8) PVLOAD(t + 1);

#pragma unroll
    for (int kk = 0; kk < 2; ++kk) {
      bf16x8 af[2];
#pragma unroll
      for (int rt = 0; rt < 2; ++rt)
        af[rt] = *(const bf16x8*)(Wv + (size_t)(i0 + rt * 16 + lr) * CDIM + t * 64 + kk * 32 + lg * 8);
#pragma unroll
      for (int ct = 0; ct < 4; ++ct) {
        const float* col = &Vsf[par][(kk * 32 + lg * 8) * 65 + ct * 16 + lr];
        fragu fu;
#pragma unroll
        for (int j = 0; j < 4; ++j)
          fu.w[j] = cvtpk(col[(2 * j) * 65], col[(2 * j + 1) * 65]);
        bf16x8 bf = fu.v;
        acc[0][ct] = MFMA16(af[0], bf, acc[0][ct]);
        acc[1][ct] = MFMA16(af[1], bf, acc[1][ct]);
      }
    }

    if (t + 1 < 8) PVWRITE((t + 1) & 1);
    __syncthreads();
  }

#pragma unroll
  for (int rt = 0; rt < 2; ++rt)
#pragma unroll
    for (int ct = 0; ct < 4; ++ct)
#pragma unroll
      for (int r = 0; r < 4; ++r) {
        int i = i0 + rt * 16 + lg * 4 + r;
        int j = j0 + ct * 16 + lr;
        D[(size_t)i * HW + j] = (u8)f8byte(acc[rt][ct][r] + bv[i]);
      }
}

// ---------------- fused flash attention: full FP8 (e4m3, K=64 MX, identity scales) ----------------
// G3 geometry (R13/R14): wave = 32q x 256c, block = 128q x 256c, grid = 512, 2 blocks/CU.
// New: Q,K fp8 [HW,64B]; Ks fp8 LDS tile (4-slot swizzle, same as V); QK = ONE
// mfma_scale_32x32x64 per 32-m strip (was 4x bf16 K=16). P/V fp8 PV as R14.
__global__ __launch_bounds__(256, 2) void flash_attn(
    const u8* __restrict__ Q, const u8* __restrict__ K, const u8* __restrict__ V,
    const float* __restrict__ value, const float* __restrict__ gammap, float* __restrict__ out)
{
  __shared__ __align__(16) u8 smem[2 * 4096 + 2 * 16384];   // Ks dbuf | Vs dbuf (40 KB)
  u8* KsB = smem;                 // [2][64 rows x 64B], 4-slot swizzle
  u8* VsB = smem + 8192;          // [2][256 rows x 64B], 4-slot swizzle

  const int b  = blockIdx.x & 7;
  const int rb = (blockIdx.x >> 3) & 31;
  const int ch = blockIdx.x >> 8;
  const int tid = threadIdx.x, wid = tid >> 6, lane = tid & 63;
  const int l31 = lane & 31, h = lane >> 5;

  const int n0 = rb * 128 + wid * 32;   // wave q-row base (32 rows)
  const int c0 = ch * 256;              // block c base (256 cols)

  const u8* Qb = Q + (size_t)b * HW * CI_;
  const u8* Kb = K + (size_t)b * HW * CI_;
  const u8* Vb = V + (size_t)b * CDIM * HW + (size_t)c0 * HW;

  // Q B-frag (fp8): col n = n0 + l31, k(ci) = 32h + reg*4 + byte
  i32x8 qfrag;
  {
    const u8* qp = Qb + (size_t)(n0 + l31) * CI_ + h * 32;
    uint4 lo = *(const uint4*)qp;
    uint4 hi = *(const uint4*)(qp + 16);
    qfrag[0] = (int)lo.x; qfrag[1] = (int)lo.y; qfrag[2] = (int)lo.z; qfrag[3] = (int)lo.w;
    qfrag[4] = (int)hi.x; qfrag[5] = (int)hi.y; qfrag[6] = (int)hi.z; qfrag[7] = (int)hi.w;
  }

  f32x16 acc[8];
#pragma unroll
  for (int ct = 0; ct < 8; ++ct)
#pragma unroll
    for (int i = 0; i < 16; ++i) acc[ct][i] = 0.f;
  float lp = 0.f;

  // ---- staging sources (pre-swizzled; involution slot ^= (row>>1)&3) ----
  const int srow8 = lane >> 2;                          // 0..15 rows/wave-instr
  const int sslot = (lane & 3) ^ ((lane >> 3) & 3);     // swizzled 16B slot
  const u8* kcur = Kb + (size_t)(wid * 16 + srow8) * CI_ + sslot * 16;  // wave: 16 K-rows
  const u8* vcur = Vb + (size_t)(wid * 64 + srow8) * HW + sslot * 16;   // wave: 64 V-rows
  const int kofs = wid * 16 * 64, vofs = wid * 64 * 64; // byte LDS offsets

#define ISSUE(BUF) do { \
    GLDS16(kcur, KsB + (BUF) * 4096 + kofs); \
    _Pragma("unroll") \
    for (int it = 0; it < 4; ++it) \
      GLDS16(vcur + (size_t)(16 * it) * HW, VsB + (BUF) * 16384 + vofs + it * 16 * 64); \
  } while (0)

  ISSUE(0);
  __syncthreads();   // compiler-inserted vmcnt(0) drains the DMA

  const int cswz = (l31 >> 1) & 3;   // read-slot swizzle for LDS row ≡ l31 (mod 32)

  for (int t = 0; t < NTIL; ++t) {
    const int par = t & 1;
    if (t + 1 < NTIL) {            // issue next-tile DMA; drains at this tile's end barrier
      kcur += MT * CI_;
      vcur += MT;
      ISSUE(par ^ 1);
    }

    // ---- QK both strips: ONE K=64 fp8 MFMA each. A=K rows (strip m), B=Q cols. ----
    f32x16 st0, st1;
    {
      const u8* ksb = KsB + par * 4096;
      const u8* k0 = ksb + (size_t)l31 * 64;
      const u8* k1 = ksb + (size_t)(32 + l31) * 64;
      uint4 lo0 = *(const uint4*)(k0 + (((2 * h)     ^ cswz) << 4));
      uint4 hi0 = *(const uint4*)(k0 + (((2 * h + 1) ^ cswz) << 4));
      uint4 lo1 = *(const uint4*)(k1 + (((2 * h)     ^ cswz) << 4));
      uint4 hi1 = *(const uint4*)(k1 + (((2 * h + 1) ^ cswz) << 4));
      i32x8 kf0, kf1;
      kf0[0] = (int)lo0.x; kf0[1] = (int)lo0.y; kf0[2] = (int)lo0.z; kf0[3] = (int)lo0.w;
      kf0[4] = (int)hi0.x; kf0[5] = (int)hi0.y; kf0[6] = (int)hi0.z; kf0[7] = (int)hi0.w;
      kf1[0] = (int)lo1.x; kf1[1] = (int)lo1.y; kf1[2] = (int)lo1.z; kf1[3] = (int)lo1.w;
      kf1[4] = (int)hi1.x; kf1[5] = (int)hi1.y; kf1[6] = (int)hi1.z; kf1[7] = (int)hi1.w;
      f32x16 z0, z1;
#pragma unroll
      for (int i = 0; i < 16; ++i) { z0[i] = 0.f; z1[i] = 0.f; }
      st0 = __builtin_amdgcn_mfma_scale_f32_32x32x64_f8f6f4(kf0, qfrag, z0, 0, 0, 0, 127, 0, 127);
      st1 = __builtin_amdgcn_mfma_scale_f32_32x32x64_f8f6f4(kf1, qfrag, z1, 0, 0, 0, 127, 0, 127);
    }

    // ---- P = exp2(S); pack to fp8; permlane-swap into one K=64 B-frag ----
    float p0[16], p1[16];
    float rs = 0.f;
#pragma unroll
    for (int r = 0; r < 16; ++r) { p0[r] = hexp2(st0[r]); rs += p0[r]; }
#pragma unroll
    for (int r = 0; r < 16; ++r) { p1[r] = hexp2(st1[r]); rs += p1[r]; }
    lp += rs;

    i32x8 pfrag;
#pragma unroll
    for (int g = 0; g < 4; ++g) {
      u32 w0 = pk4fp8(p0[4 * g], p0[4 * g + 1], p0[4 * g + 2], p0[4 * g + 3]);
      u32 w1 = pk4fp8(p1[4 * g], p1[4 * g + 1], p1[4 * g + 2], p1[4 * g + 3]);
      asm("v_permlane32_swap_b32 %0, %1" : "+v"(w0), "+v"(w1));
      pfrag[2 * g]     = (int)w0;
      pfrag[2 * g + 1] = (int)w1;
    }

    // ---- PV: one K=64 fp8 MFMA per ct (scales = 1.0) ----
    __builtin_amdgcn_s_setprio(1);
#pragma unroll
    for (int ct = 0; ct < 8; ++ct) {
      const u8* vb = VsB + par * 16384 + (size_t)(ct * 32 + l31) * 64;
      uint4 lo = *(const uint4*)(vb + (((2 * h)     ^ cswz) << 4));
      uint4 hi = *(const uint4*)(vb + (((2 * h + 1) ^ cswz) << 4));
      i32x8 vfrag;
      vfrag[0] = (int)lo.x; vfrag[1] = (int)lo.y; vfrag[2] = (int)lo.z; vfrag[3] = (int)lo.w;
      vfrag[4] = (int)hi.x; vfrag[5] = (int)hi.y; vfrag[6] = (int)hi.z; vfrag[7] = (int)hi.w;
      acc[ct] = __builtin_amdgcn_mfma_scale_f32_32x32x64_f8f6f4(
                    vfrag, pfrag, acc[ct], 0, 0, 0, 127, 0, 127);
    }
    __builtin_amdgcn_s_setprio(0);

    __syncthreads();   // single barrier: drains next-tile DMA + fences dbuf parity
  }

  // ---- epilogue: per-wave LDS transpose so value/out stay coalesced ----
  __syncthreads();   // everyone done with Ks/Vs; reuse smem as scratch
  float* Tls = (float*)(smem + wid * 4352);  // 32c x 33n f32 per wave (17408B total < 40KB)
  const float g = gammap[0];
  const float ls = lp + __shfl_xor(lp, 32);
  const float ri = g / ls;                    // lane's n = l31
  const size_t obase = (size_t)b * CDIM * HW;
#pragma unroll
  for (int ct = 0; ct < 8; ++ct) {
    // write: Tls[c_local][n_local]
#pragma unroll
    for (int r = 0; r < 16; ++r) {
      int cc = (r & 3) + 8 * (r >> 2) + 4 * h;
      Tls[cc * 33 + l31] = acc[ct][r] * ri;
    }
    // read coalesced: lane -> c = l31, n = 2p + h
#pragma unroll
    for (int p = 0; p < 16; ++p) {
      float v = Tls[l31 * 33 + 2 * p + h];
      int n = n0 + 2 * p + h;
      int c = c0 + ct * 32 + l31;
      size_t idx = obase + (size_t)n * CDIM + c;
      out[idx] = v + value[idx];
    }
  }
}

extern "C" void kernel_launch(void* const* d_in, const int* in_sizes, int n_in,
                              void* d_out, int out_size, void* d_ws, size_t ws_size,
                              hipStream_t stream) {
  const float* query = (const float*)d_in[0];
  const float* key   = (const float*)d_in[1];
  const float* value = (const float*)d_in[2];
  const float* Wq    = (const float*)d_in[3];
  const float* bq    = (const float*)d_in[4];
  const float* Wk    = (const float*)d_in[5];
  const float* bk    = (const float*)d_in[6];
  const float* Wv    = (const float*)d_in[7];
  const float* bv    = (const float*)d_in[8];
  const float* gamma = (const float*)d_in[9];

  char* ws = (char*)d_ws;
  u8*  Qb  = (u8*)(ws);                //  2,097,152 B  [B,HW,64] e4m3fn
  u8*  Kb  = (u8*)(ws + 2097152);      //  2,097,152 B  [B,HW,64] e4m3fn
  u8*  Vb  = (u8*)(ws + 4194304);      // 16,777,216 B  [B,C,HW] e4m3fn V^T
  u16* WQb = (u16*)(ws + 20971520);    //     65,536 B
  u16* WKb = (u16*)(ws + 21037056);    //     65,536 B
  u16* WVb = (u16*)(ws + 21102592);    //    524,288 B

  // 1) weight casts
  cast3<<<(CDIM * CDIM) / 256, 256, 0, stream>>>(Wq, Wk, Wv, WQb, WKb, WVb);

  // 2) Q and K projections with fused transpose+cast -> fp8 (z<8: Q, z>=8: K)
  proj_qk<<<dim3(HW / 128, 1, 16), 256, 0, stream>>>(
      query, key, WQb, WKb, bq, bk, Qb, Kb);

  // 3) V^T projection with fused transpose+cast -> [B, C, HW] fp8
  proj_v<<<dim3(CDIM / 128, HW / 64, B_), 256, 0, stream>>>(
      value, WVb, bv, Vb);

  // 4) fused flash attention + epilogue (full fp8 MFMA path)
  flash_attn<<<512, 256, 0, stream>>>(Qb, Kb, Vb, value, gamma, (float*)d_out);
}